// Round 7
// baseline (542.839 us; speedup 1.0000x reference)
//
#include <hip/hip_runtime.h>
#include <hip/hip_bf16.h>

#define NROWS 8192
#define FD 256
#define NA 256
#define NH 16
#define NB 32      // n-rows per main block
#define AB 64      // a-cols per main block

typedef __attribute__((ext_vector_type(2))) float f32x2;
typedef __attribute__((ext_vector_type(4))) float f32x4;
typedef __attribute__((ext_vector_type(8))) __bf16 bf16x8;
typedef __attribute__((ext_vector_type(8))) unsigned short ushort8;
typedef __attribute__((ext_vector_type(2))) _Float16 h16x2;
typedef __attribute__((ext_vector_type(4))) _Float16 h16x4;
typedef __attribute__((ext_vector_type(8))) _Float16 h16x8;

struct h2q { h16x2 p[4]; };

__device__ __forceinline__ unsigned short f2bf(float x) {
    unsigned int u = __builtin_bit_cast(unsigned int, x);
    u += 0x7FFFu + ((u >> 16) & 1u);
    return (unsigned short)(u >> 16);
}

// |a + b| on 8 f16, h16x2-granular so the backend emits 4x v_pk_add_f16
// (half-rate) + 4x v_and_b32 (full-rate). No h16x8-wide ops, no asm.
__device__ __forceinline__ h16x8 absadd(h16x8 a, h16x8 b) {
    h2q A = __builtin_bit_cast(h2q, a), B = __builtin_bit_cast(h2q, b), R;
#pragma unroll
    for (int q = 0; q < 4; ++q) {
        h16x2 t = A.p[q] + B.p[q];                                   // v_pk_add_f16
        unsigned int u = __builtin_bit_cast(unsigned int, t) & 0x7FFF7FFFu; // v_and_b32
        R.p[q] = __builtin_bit_cast(h16x2, u);
    }
    return __builtin_bit_cast(h16x8, R);
}

// ---------------- cvt kernels ----------------
__global__ __launch_bounds__(256) void cvt_x_kernel(const float* __restrict__ src,
                                                    unsigned short* __restrict__ dst) {
    size_t i = (size_t)blockIdx.x * 256 + threadIdx.x;
    const f32x4* s = (const f32x4*)(src + i * 8);
    f32x4 a = s[0], b = s[1];
    ushort8 o;
    o[0] = f2bf(a.x); o[1] = f2bf(a.y); o[2] = f2bf(a.z); o[3] = f2bf(a.w);
    o[4] = f2bf(b.x); o[5] = f2bf(b.y); o[6] = f2bf(b.z); o[7] = f2bf(b.w);
    *(ushort8*)(dst + i * 8) = o;
}

__global__ __launch_bounds__(256) void cvt_w_kernel(const float* __restrict__ W1,
                                                    unsigned short* __restrict__ dst) {
    size_t i = (size_t)blockIdx.x * 256 + threadIdx.x;
    int k = ((int)i & 31) * 8;
    int f = ((int)(i >> 5)) & 255;
    int h = (int)(i >> 13);
    const float* s = W1 + ((size_t)(h * 256 + f)) * 512 + k;   // W1x part
    const f32x4* s4 = (const f32x4*)s;
    f32x4 a = s4[0], b = s4[1];
    ushort8 o;
    o[0] = f2bf(a.x); o[1] = f2bf(a.y); o[2] = f2bf(a.z); o[3] = f2bf(a.w);
    o[4] = f2bf(b.x); o[5] = f2bf(b.y); o[6] = f2bf(b.z); o[7] = f2bf(b.w);
    *(ushort8*)(dst + i * 8) = o;
}

// W2h = 0.5 * W2 in f16 — the 1/2 of the abs identity is folded here.
__global__ __launch_bounds__(256) void cvt_w2_kernel(const float* __restrict__ W2,
                                                     _Float16* __restrict__ W2h) {
    int i = blockIdx.x * 256 + threadIdx.x;
    W2h[i] = (_Float16)(W2[i] * 0.5f);
}

// ---------------- G = anchors @ W1a^T + b1  (f16 output) ----------------
__global__ __launch_bounds__(256) void g_kernel(const float* __restrict__ anchors,
                                                const float* __restrict__ W1,
                                                const float* __restrict__ b1,
                                                _Float16* __restrict__ Gh) {
    __shared__ float anc_s[64][68];
    __shared__ float w_s[64][68];
    int h = blockIdx.x, a0 = blockIdx.y * 64, f0 = blockIdx.z * 64;
    int tid = threadIdx.x;
    int tf = tid & 15, av = tid >> 4;
    float acc[4][4] = {};
    int sr = tid >> 2, sc = (tid & 3) * 16;
    for (int kc = 0; kc < 4; ++kc) {
        int k0 = kc * 64;
        __syncthreads();
        {
            const float* s = anchors + (size_t)(a0 + sr) * FD + k0 + sc;
            const float* w = W1 + ((size_t)(h * 256 + f0 + sr)) * 512 + 256 + k0 + sc;
#pragma unroll
            for (int q = 0; q < 4; ++q) {
                *(f32x4*)&anc_s[sr][sc + q * 4] = *(const f32x4*)(s + q * 4);
                *(f32x4*)&w_s[sr][sc + q * 4]   = *(const f32x4*)(w + q * 4);
            }
        }
        __syncthreads();
#pragma unroll 8
        for (int k = 0; k < 64; ++k) {
            float avv[4], wvv[4];
#pragma unroll
            for (int ia = 0; ia < 4; ++ia) avv[ia] = anc_s[av + 16 * ia][k];
#pragma unroll
            for (int jf = 0; jf < 4; ++jf) wvv[jf] = w_s[tf + 16 * jf][k];
#pragma unroll
            for (int ia = 0; ia < 4; ++ia)
#pragma unroll
                for (int jf = 0; jf < 4; ++jf)
                    acc[ia][jf] = fmaf(avv[ia], wvv[jf], acc[ia][jf]);
        }
    }
#pragma unroll
    for (int ia = 0; ia < 4; ++ia) {
        int a = a0 + av + 16 * ia;
#pragma unroll
        for (int jf = 0; jf < 4; ++jf) {
            int f = f0 + tf + 16 * jf;
            Gh[((size_t)(h * 256 + a)) * FD + f] = (_Float16)(acc[ia][jf] + b1[h * 256 + f]);
        }
    }
}

// ---------------- dga[h,a] = sum_f Gh*W2h + b2 ----------------
__global__ __launch_bounds__(256) void dga_kernel(const _Float16* __restrict__ Gh,
                                                  const _Float16* __restrict__ W2h,
                                                  const float* __restrict__ b2,
                                                  float* __restrict__ dga) {
    int h = blockIdx.x, a = threadIdx.x;
    const _Float16* gp = Gh + ((size_t)(h * NA + a)) * FD;
    const _Float16* wp = W2h + h * FD;
    float p = b2[h];
#pragma unroll 4
    for (int c = 0; c < 32; ++c) {
        h2q gv = __builtin_bit_cast(h2q, *(const h16x8*)(gp + c * 8));
        h2q wv = __builtin_bit_cast(h2q, *(const h16x8*)(wp + c * 8));
#pragma unroll
        for (int q = 0; q < 4; ++q) p = __builtin_amdgcn_fdot2(gv.p[q], wv.p[q], p, false);
    }
    dga[h * NA + a] = p;
}

// ---------------- dhx[lh,n] = sum_f HXh*W2h ----------------
__global__ __launch_bounds__(256) void dhx_kernel(const _Float16* __restrict__ HXh,
                                                  const _Float16* __restrict__ W2h,
                                                  float* __restrict__ dhx, int h0) {
    int lh = blockIdx.y;
    int n = blockIdx.x * 64 + (threadIdx.x >> 2);
    int fq = threadIdx.x & 3;
    const _Float16* hp = HXh + ((size_t)lh * NROWS + n) * FD + fq * 64;
    const _Float16* wp = W2h + (h0 + lh) * FD + fq * 64;
    float p = 0.0f;
#pragma unroll
    for (int c = 0; c < 8; ++c) {
        h2q hv = __builtin_bit_cast(h2q, *(const h16x8*)(hp + c * 8));
        h2q wv = __builtin_bit_cast(h2q, *(const h16x8*)(wp + c * 8));
#pragma unroll
        for (int q = 0; q < 4; ++q) p = __builtin_amdgcn_fdot2(hv.p[q], wv.p[q], p, false);
    }
    p += __shfl_xor(p, 1);
    p += __shfl_xor(p, 2);
    if (fq == 0) dhx[(size_t)lh * NROWS + n] = p;
}

// ---------------- HX = context @ W1x^T (bf16 MFMA, f16 output) ----------------
__global__ __launch_bounds__(256) void hx_kernel(const unsigned short* __restrict__ Xb,
                                                 const unsigned short* __restrict__ Wb,
                                                 _Float16* __restrict__ HXh,
                                                 int h0) {
    __shared__ unsigned short xs[128][40];
    __shared__ unsigned short ws2[128][40];
    int n0 = blockIdx.x * 128;
    int fg0 = blockIdx.y * 128;
    int lh = fg0 >> 8;
    int f0 = fg0 & 255;
    int h = h0 + lh;
    int tid = threadIdx.x;
    int w = tid >> 6, lane = tid & 63;
    int wn = w & 1, wf = w >> 1;
    int arow = lane & 15, kg = lane >> 4;
    f32x4 acc[4][4] = {};
    int sr = tid >> 1, sc = (tid & 1) * 16;
    for (int kk = 0; kk < 8; ++kk) {
        int k0 = kk * 32;
        __syncthreads();
        {
            const ushort8* sx = (const ushort8*)(Xb + (size_t)(n0 + sr) * FD + k0 + sc);
            *(ushort8*)&xs[sr][sc]     = sx[0];
            *(ushort8*)&xs[sr][sc + 8] = sx[1];
            const ushort8* sw = (const ushort8*)(Wb + ((size_t)(h * 256 + f0 + sr)) * FD + k0 + sc);
            *(ushort8*)&ws2[sr][sc]     = sw[0];
            *(ushort8*)&ws2[sr][sc + 8] = sw[1];
        }
        __syncthreads();
        bf16x8 af[4], bfv[4];
#pragma unroll
        for (int i = 0; i < 4; ++i)
            af[i] = __builtin_bit_cast(bf16x8, *(const ushort8*)&xs[wn * 64 + i * 16 + arow][kg * 8]);
#pragma unroll
        for (int j = 0; j < 4; ++j)
            bfv[j] = __builtin_bit_cast(bf16x8, *(const ushort8*)&ws2[wf * 64 + j * 16 + arow][kg * 8]);
#pragma unroll
        for (int i = 0; i < 4; ++i)
#pragma unroll
            for (int j = 0; j < 4; ++j)
                acc[i][j] = __builtin_amdgcn_mfma_f32_16x16x32_bf16(af[i], bfv[j], acc[i][j], 0, 0, 0);
    }
#pragma unroll
    for (int i = 0; i < 4; ++i) {
        int nr = n0 + wn * 64 + i * 16 + kg * 4;
#pragma unroll
        for (int j = 0; j < 4; ++j) {
            int fc = f0 + wf * 64 + j * 16 + arow;
#pragma unroll
            for (int r = 0; r < 4; ++r)
                HXh[((size_t)lh * NROWS + nr + r) * FD + fc] = (_Float16)acc[i][j][r];
        }
    }
}

// ------- main: |hx+g| dot (w2/2) via MFMA; 2 a-groups/wave, real pipeline -------
__global__ __launch_bounds__(256, 3) void main5_kernel(const _Float16* __restrict__ HXh,
                                                       const _Float16* __restrict__ Gh,
                                                       const _Float16* __restrict__ W2h,
                                                       const float* __restrict__ dhx,
                                                       const float* __restrict__ dga,
                                                       float* __restrict__ out,
                                                       int h0, int hcnt) {
    __shared__ _Float16 hxs[2][NB][FD];     // 32 KB double-buffered hx tile
    __shared__ _Float16 score_s[NB][AB];    // 4 KB
    __shared__ float dhx_s[2][NB];
    __shared__ float dga_s[2][AB];
    int tid = threadIdx.x;
    int lane = tid & 63, w = tid >> 6;
    int arow = lane & 15, grp = lane >> 4;
    int wn = w & 1;          // n-half owned by this wave
    int wa = w >> 1;         // a-half owned by this wave (2 groups of 16)
    int n0 = blockIdx.x * NB, a0 = blockIdx.y * AB;
    const h16x8 hzero = {0, 0, 0, 0, 0, 0, 0, 0};
    float att[8] = {};

    // prologue: prefetch head 0's hx tile + dhx/dga into registers
    h16x8 px0, px1, px2, px3;
    float pdhx = 0.0f, pdga = 0.0f;
    {
        const h16x8* src = (const h16x8*)(HXh + (size_t)n0 * FD);
        px0 = src[tid]; px1 = src[tid + 256]; px2 = src[tid + 512]; px3 = src[tid + 768];
        if (tid < NB) pdhx = dhx[n0 + tid];
        if (tid >= 64 && tid < 64 + AB) pdga = dga[h0 * NA + a0 + (tid - 64)];
    }

#pragma unroll 1
    for (int lh = 0; lh < hcnt; ++lh) {
        int h = h0 + lh, buf = lh & 1;
        // current head's fragments: 2 a-groups of G + the w2 column
        h16x8 gcur[2][8], bcur[8];
#pragma unroll
        for (int fc = 0; fc < 8; ++fc) {
            gcur[0][fc] = *(const h16x8*)(Gh + ((size_t)(h * NA + a0 + wa * 32 + arow)) * FD + fc * 32 + grp * 8);
            gcur[1][fc] = *(const h16x8*)(Gh + ((size_t)(h * NA + a0 + wa * 32 + 16 + arow)) * FD + fc * 32 + grp * 8);
            h16x8 wv = *(const h16x8*)(W2h + h * FD + fc * 32 + grp * 8);
            bcur[fc] = (arow == 0) ? wv : hzero;
        }
        // stage prefetched tile into LDS (px regs consumed here, pre-barrier)
        {
            h16x8* d = (h16x8*)&hxs[buf][0][0];
            d[tid] = px0; d[tid + 256] = px1; d[tid + 512] = px2; d[tid + 768] = px3;
        }
        if (tid < NB) dhx_s[buf][tid] = pdhx;
        if (tid >= 64 && tid < 64 + AB) dga_s[buf][tid - 64] = pdga;
        __syncthreads();
        // issue next head's prefetch AFTER the barrier so it overlaps the n-loop
        // (any vmem issued pre-barrier is drained by the barrier's vmcnt(0))
        if (lh + 1 < hcnt) {
            const h16x8* src = (const h16x8*)(HXh + ((size_t)(lh + 1) * NROWS + n0) * FD);
            px0 = src[tid]; px1 = src[tid + 256]; px2 = src[tid + 512]; px3 = src[tid + 768];
            if (tid < NB) pdhx = dhx[(size_t)(lh + 1) * NROWS + n0 + tid];
            if (tid >= 64 && tid < 64 + AB) pdga = dga[(h + 1) * NA + a0 + (tid - 64)];
        }
        // n-loop: each wave does its n-half x its 2 a-groups.
        // 1 ds_read feeds 2 MFMAs (one per a-group).
#pragma unroll 1
        for (int nn = 0; nn < NB / 2; nn += 2) {
            int n = wn * (NB / 2) + nn;
            f32x4 a00 = {0, 0, 0, 0}, a10 = {0, 0, 0, 0};
            f32x4 a01 = {0, 0, 0, 0}, a11 = {0, 0, 0, 0};
#pragma unroll
            for (int fc = 0; fc < 8; ++fc) {
                h16x8 hx0 = *(const h16x8*)&hxs[buf][n][fc * 32 + grp * 8];
                h16x8 hx1 = *(const h16x8*)&hxs[buf][n + 1][fc * 32 + grp * 8];
                a00 = __builtin_amdgcn_mfma_f32_16x16x32_f16(absadd(hx0, gcur[0][fc]), bcur[fc], a00, 0, 0, 0);
                a10 = __builtin_amdgcn_mfma_f32_16x16x32_f16(absadd(hx0, gcur[1][fc]), bcur[fc], a10, 0, 0, 0);
                a01 = __builtin_amdgcn_mfma_f32_16x16x32_f16(absadd(hx1, gcur[0][fc]), bcur[fc], a01, 0, 0, 0);
                a11 = __builtin_amdgcn_mfma_f32_16x16x32_f16(absadd(hx1, gcur[1][fc]), bcur[fc], a11, 0, 0, 0);
            }
            if (arow == 0) {   // D col0: row a = grp*4 + r
                h16x4 s;
                s = (h16x4){(_Float16)a00.x, (_Float16)a00.y, (_Float16)a00.z, (_Float16)a00.w};
                *(h16x4*)&score_s[n][wa * 32 + grp * 4]          = s;
                s = (h16x4){(_Float16)a10.x, (_Float16)a10.y, (_Float16)a10.z, (_Float16)a10.w};
                *(h16x4*)&score_s[n][wa * 32 + 16 + grp * 4]     = s;
                s = (h16x4){(_Float16)a01.x, (_Float16)a01.y, (_Float16)a01.z, (_Float16)a01.w};
                *(h16x4*)&score_s[n + 1][wa * 32 + grp * 4]      = s;
                s = (h16x4){(_Float16)a11.x, (_Float16)a11.y, (_Float16)a11.z, (_Float16)a11.w};
                *(h16x4*)&score_s[n + 1][wa * 32 + 16 + grp * 4] = s;
            }
        }
        __syncthreads();
        // epilogue: sigmoid + head-accumulate (att in registers)
#pragma unroll
        for (int e = 0; e < 8; ++e) {
            int idx = tid + e * 256, n = idx >> 6, a = idx & 63;
            float sc = (float)score_s[n][a] + dhx_s[buf][n] + dga_s[buf][a];
            att[e] += 1.0f / (1.0f + __expf(-sc));
        }
    }
#pragma unroll
    for (int e = 0; e < 8; ++e) {
        int idx = tid + e * 256, n = idx >> 6, a = idx & 63;
        atomicAdd(&out[(size_t)(n0 + n) * NA + a0 + a], att[e] * (1.0f / 16.0f));
    }
}

extern "C" void kernel_launch(void* const* d_in, const int* in_sizes, int n_in,
                              void* d_out, int out_size, void* d_ws, size_t ws_size,
                              hipStream_t stream) {
    const float* ctx     = (const float*)d_in[0];
    const float* anchors = (const float*)d_in[1];
    const float* W1      = (const float*)d_in[2];
    const float* b1      = (const float*)d_in[3];
    const float* W2      = (const float*)d_in[4];
    const float* b2      = (const float*)d_in[5];
    float* out = (float*)d_out;
    char* ws = (char*)d_ws;

    const size_t SZ_G   = (size_t)NH * NA * FD * 2;
    const size_t SZ_XB  = (size_t)NROWS * FD * 2;
    const size_t SZ_WB  = (size_t)NH * FD * FD * 2;
    const size_t SZ_W2  = (size_t)NH * FD * 2;
    const size_t SZ_DGA = (size_t)NH * NA * 4;
    const size_t SZ_DHX = (size_t)NH * NROWS * 4;
    const size_t SZ_HX1 = (size_t)NROWS * FD * 2;
    const size_t fixed = SZ_G + SZ_XB + SZ_WB + SZ_W2 + SZ_DGA + SZ_DHX;

    int HG;
    if      (ws_size >= fixed + 16 * SZ_HX1) HG = 16;
    else if (ws_size >= fixed + 4 * SZ_HX1)  HG = 4;
    else if (ws_size >= fixed + 2 * SZ_HX1)  HG = 2;
    else                                      HG = 1;

    _Float16* Gh       = (_Float16*)(ws);
    unsigned short* Xb = (unsigned short*)(ws + SZ_G);
    unsigned short* Wb = (unsigned short*)(ws + SZ_G + SZ_XB);
    _Float16* W2h      = (_Float16*)(ws + SZ_G + SZ_XB + SZ_WB);
    float* dga         = (float*)(ws + SZ_G + SZ_XB + SZ_WB + SZ_W2);
    float* dhx         = (float*)(ws + SZ_G + SZ_XB + SZ_WB + SZ_W2 + SZ_DGA);
    _Float16* HXh      = (_Float16*)(ws + fixed);

    hipMemsetAsync(out, 0, (size_t)NROWS * NA * sizeof(float), stream);
    cvt_x_kernel<<<1024, 256, 0, stream>>>(ctx, Xb);
    cvt_w_kernel<<<512, 256, 0, stream>>>(W1, Wb);
    cvt_w2_kernel<<<16, 256, 0, stream>>>(W2, W2h);
    g_kernel<<<dim3(16, 4, 4), 256, 0, stream>>>(anchors, W1, b1, Gh);
    dga_kernel<<<16, 256, 0, stream>>>(Gh, W2h, b2, dga);

    for (int h0 = 0; h0 < NH; h0 += HG) {
        hx_kernel<<<dim3(64, HG * 2), 256, 0, stream>>>(Xb, Wb, HXh, h0);
        dhx_kernel<<<dim3(128, HG), 256, 0, stream>>>(HXh, W2h, dhx, h0);
        main5_kernel<<<dim3(NROWS / NB, NA / AB), 256, 0, stream>>>(HXh, Gh, W2h, dhx, dga, out, h0, HG);
    }
    hipMemcpyAsync(out + (size_t)NROWS * NA, anchors, (size_t)NA * FD * sizeof(float),
                   hipMemcpyDeviceToDevice, stream);
}

// Round 8
// 420.227 us; speedup vs baseline: 1.2918x; 1.2918x over previous
//
#include <hip/hip_runtime.h>
#include <hip/hip_bf16.h>

#define NROWS 8192
#define FD 256
#define NA 256
#define NH 16
#define NB 32      // n-rows per main block
#define AB 64      // a-cols per main block

typedef __attribute__((ext_vector_type(2))) float f32x2;
typedef __attribute__((ext_vector_type(4))) float f32x4;
typedef __attribute__((ext_vector_type(8))) __bf16 bf16x8;
typedef __attribute__((ext_vector_type(8))) unsigned short ushort8;
typedef __attribute__((ext_vector_type(2))) _Float16 h16x2;
typedef __attribute__((ext_vector_type(4))) _Float16 h16x4;
typedef __attribute__((ext_vector_type(8))) _Float16 h16x8;

struct h2q { h16x2 p[4]; };

__device__ __forceinline__ unsigned short f2bf(float x) {
    unsigned int u = __builtin_bit_cast(unsigned int, x);
    u += 0x7FFFu + ((u >> 16) & 1u);
    return (unsigned short)(u >> 16);
}

// |a + b| on 8 f16: 4x v_pk_add_f16 + 4x v_and_b32 (h16x2-granular, no asm).
__device__ __forceinline__ h16x8 absadd(h16x8 a, h16x8 b) {
    h2q A = __builtin_bit_cast(h2q, a), B = __builtin_bit_cast(h2q, b), R;
#pragma unroll
    for (int q = 0; q < 4; ++q) {
        h16x2 t = A.p[q] + B.p[q];                                    // v_pk_add_f16
        unsigned int u = __builtin_bit_cast(unsigned int, t) & 0x7FFF7FFFu; // v_and_b32
        R.p[q] = __builtin_bit_cast(h16x2, u);
    }
    return __builtin_bit_cast(h16x8, R);
}

// ---------------- cvt kernels ----------------
__global__ __launch_bounds__(256) void cvt_x_kernel(const float* __restrict__ src,
                                                    unsigned short* __restrict__ dst) {
    size_t i = (size_t)blockIdx.x * 256 + threadIdx.x;
    const f32x4* s = (const f32x4*)(src + i * 8);
    f32x4 a = s[0], b = s[1];
    ushort8 o;
    o[0] = f2bf(a.x); o[1] = f2bf(a.y); o[2] = f2bf(a.z); o[3] = f2bf(a.w);
    o[4] = f2bf(b.x); o[5] = f2bf(b.y); o[6] = f2bf(b.z); o[7] = f2bf(b.w);
    *(ushort8*)(dst + i * 8) = o;
}

__global__ __launch_bounds__(256) void cvt_w_kernel(const float* __restrict__ W1,
                                                    unsigned short* __restrict__ dst) {
    size_t i = (size_t)blockIdx.x * 256 + threadIdx.x;
    int k = ((int)i & 31) * 8;
    int f = ((int)(i >> 5)) & 255;
    int h = (int)(i >> 13);
    const float* s = W1 + ((size_t)(h * 256 + f)) * 512 + k;   // W1x part
    const f32x4* s4 = (const f32x4*)s;
    f32x4 a = s4[0], b = s4[1];
    ushort8 o;
    o[0] = f2bf(a.x); o[1] = f2bf(a.y); o[2] = f2bf(a.z); o[3] = f2bf(a.w);
    o[4] = f2bf(b.x); o[5] = f2bf(b.y); o[6] = f2bf(b.z); o[7] = f2bf(b.w);
    *(ushort8*)(dst + i * 8) = o;
}

// W2h = 0.5 * W2 in f16 — the 1/2 of the abs identity is folded here.
__global__ __launch_bounds__(256) void cvt_w2_kernel(const float* __restrict__ W2,
                                                     _Float16* __restrict__ W2h) {
    int i = blockIdx.x * 256 + threadIdx.x;
    W2h[i] = (_Float16)(W2[i] * 0.5f);
}

// ---------------- G = anchors @ W1a^T + b1  (f16 output) ----------------
__global__ __launch_bounds__(256) void g_kernel(const float* __restrict__ anchors,
                                                const float* __restrict__ W1,
                                                const float* __restrict__ b1,
                                                _Float16* __restrict__ Gh) {
    __shared__ float anc_s[64][68];
    __shared__ float w_s[64][68];
    int h = blockIdx.x, a0 = blockIdx.y * 64, f0 = blockIdx.z * 64;
    int tid = threadIdx.x;
    int tf = tid & 15, av = tid >> 4;
    float acc[4][4] = {};
    int sr = tid >> 2, sc = (tid & 3) * 16;
    for (int kc = 0; kc < 4; ++kc) {
        int k0 = kc * 64;
        __syncthreads();
        {
            const float* s = anchors + (size_t)(a0 + sr) * FD + k0 + sc;
            const float* w = W1 + ((size_t)(h * 256 + f0 + sr)) * 512 + 256 + k0 + sc;
#pragma unroll
            for (int q = 0; q < 4; ++q) {
                *(f32x4*)&anc_s[sr][sc + q * 4] = *(const f32x4*)(s + q * 4);
                *(f32x4*)&w_s[sr][sc + q * 4]   = *(const f32x4*)(w + q * 4);
            }
        }
        __syncthreads();
#pragma unroll 8
        for (int k = 0; k < 64; ++k) {
            float avv[4], wvv[4];
#pragma unroll
            for (int ia = 0; ia < 4; ++ia) avv[ia] = anc_s[av + 16 * ia][k];
#pragma unroll
            for (int jf = 0; jf < 4; ++jf) wvv[jf] = w_s[tf + 16 * jf][k];
#pragma unroll
            for (int ia = 0; ia < 4; ++ia)
#pragma unroll
                for (int jf = 0; jf < 4; ++jf)
                    acc[ia][jf] = fmaf(avv[ia], wvv[jf], acc[ia][jf]);
        }
    }
#pragma unroll
    for (int ia = 0; ia < 4; ++ia) {
        int a = a0 + av + 16 * ia;
#pragma unroll
        for (int jf = 0; jf < 4; ++jf) {
            int f = f0 + tf + 16 * jf;
            Gh[((size_t)(h * 256 + a)) * FD + f] = (_Float16)(acc[ia][jf] + b1[h * 256 + f]);
        }
    }
}

// ---------------- dga[h,a] = sum_f Gh*W2h + b2 ----------------
__global__ __launch_bounds__(256) void dga_kernel(const _Float16* __restrict__ Gh,
                                                  const _Float16* __restrict__ W2h,
                                                  const float* __restrict__ b2,
                                                  float* __restrict__ dga) {
    int h = blockIdx.x, a = threadIdx.x;
    const _Float16* gp = Gh + ((size_t)(h * NA + a)) * FD;
    const _Float16* wp = W2h + h * FD;
    float p = b2[h];
#pragma unroll 4
    for (int c = 0; c < 32; ++c) {
        h2q gv = __builtin_bit_cast(h2q, *(const h16x8*)(gp + c * 8));
        h2q wv = __builtin_bit_cast(h2q, *(const h16x8*)(wp + c * 8));
#pragma unroll
        for (int q = 0; q < 4; ++q) p = __builtin_amdgcn_fdot2(gv.p[q], wv.p[q], p, false);
    }
    dga[h * NA + a] = p;
}

// ---------------- dhx[lh,n] = sum_f HXh*W2h ----------------
__global__ __launch_bounds__(256) void dhx_kernel(const _Float16* __restrict__ HXh,
                                                  const _Float16* __restrict__ W2h,
                                                  float* __restrict__ dhx, int h0) {
    int lh = blockIdx.y;
    int n = blockIdx.x * 64 + (threadIdx.x >> 2);
    int fq = threadIdx.x & 3;
    const _Float16* hp = HXh + ((size_t)lh * NROWS + n) * FD + fq * 64;
    const _Float16* wp = W2h + (h0 + lh) * FD + fq * 64;
    float p = 0.0f;
#pragma unroll
    for (int c = 0; c < 8; ++c) {
        h2q hv = __builtin_bit_cast(h2q, *(const h16x8*)(hp + c * 8));
        h2q wv = __builtin_bit_cast(h2q, *(const h16x8*)(wp + c * 8));
#pragma unroll
        for (int q = 0; q < 4; ++q) p = __builtin_amdgcn_fdot2(hv.p[q], wv.p[q], p, false);
    }
    p += __shfl_xor(p, 1);
    p += __shfl_xor(p, 2);
    if (fq == 0) dhx[(size_t)lh * NROWS + n] = p;
}

// ---------------- HX = context @ W1x^T (bf16 MFMA, f16 output) ----------------
__global__ __launch_bounds__(256) void hx_kernel(const unsigned short* __restrict__ Xb,
                                                 const unsigned short* __restrict__ Wb,
                                                 _Float16* __restrict__ HXh,
                                                 int h0) {
    __shared__ unsigned short xs[128][40];
    __shared__ unsigned short ws2[128][40];
    int n0 = blockIdx.x * 128;
    int fg0 = blockIdx.y * 128;
    int lh = fg0 >> 8;
    int f0 = fg0 & 255;
    int h = h0 + lh;
    int tid = threadIdx.x;
    int w = tid >> 6, lane = tid & 63;
    int wn = w & 1, wf = w >> 1;
    int arow = lane & 15, kg = lane >> 4;
    f32x4 acc[4][4] = {};
    int sr = tid >> 1, sc = (tid & 1) * 16;
    for (int kk = 0; kk < 8; ++kk) {
        int k0 = kk * 32;
        __syncthreads();
        {
            const ushort8* sx = (const ushort8*)(Xb + (size_t)(n0 + sr) * FD + k0 + sc);
            *(ushort8*)&xs[sr][sc]     = sx[0];
            *(ushort8*)&xs[sr][sc + 8] = sx[1];
            const ushort8* sw = (const ushort8*)(Wb + ((size_t)(h * 256 + f0 + sr)) * FD + k0 + sc);
            *(ushort8*)&ws2[sr][sc]     = sw[0];
            *(ushort8*)&ws2[sr][sc + 8] = sw[1];
        }
        __syncthreads();
        bf16x8 af[4], bfv[4];
#pragma unroll
        for (int i = 0; i < 4; ++i)
            af[i] = __builtin_bit_cast(bf16x8, *(const ushort8*)&xs[wn * 64 + i * 16 + arow][kg * 8]);
#pragma unroll
        for (int j = 0; j < 4; ++j)
            bfv[j] = __builtin_bit_cast(bf16x8, *(const ushort8*)&ws2[wf * 64 + j * 16 + arow][kg * 8]);
#pragma unroll
        for (int i = 0; i < 4; ++i)
#pragma unroll
            for (int j = 0; j < 4; ++j)
                acc[i][j] = __builtin_amdgcn_mfma_f32_16x16x32_bf16(af[i], bfv[j], acc[i][j], 0, 0, 0);
    }
#pragma unroll
    for (int i = 0; i < 4; ++i) {
        int nr = n0 + wn * 64 + i * 16 + kg * 4;
#pragma unroll
        for (int j = 0; j < 4; ++j) {
            int fc = f0 + wf * 64 + j * 16 + arow;
#pragma unroll
            for (int r = 0; r < 4; ++r)
                HXh[((size_t)lh * NROWS + nr + r) * FD + fc] = (_Float16)acc[i][j][r];
        }
    }
}

// ------- main: |hx+g| dot (w2/2) via MFMA; round-3 structure, 4 heads/block -------
__global__ __launch_bounds__(256, 4) void main6_kernel(const _Float16* __restrict__ HXh,
                                                       const _Float16* __restrict__ Gh,
                                                       const _Float16* __restrict__ W2h,
                                                       const float* __restrict__ dhx,
                                                       const float* __restrict__ dga,
                                                       float* __restrict__ out,
                                                       int h0, int hpb) {
    __shared__ _Float16 hxs[NB][FD];        // 16 KB
    __shared__ _Float16 score_s[NB][AB];    // 4 KB
    __shared__ float att_s[NB][AB];         // 8 KB
    __shared__ float dhx_s[NB];
    __shared__ float dga_s[AB];
    int tid = threadIdx.x;
    int lane = tid & 63, w = tid >> 6;
    int arow = lane & 15, grp = lane >> 4;
    int n0 = blockIdx.x * NB, a0 = blockIdx.y * AB;
    int hb = blockIdx.z * hpb;              // buffer-head base
    int a_base = a0 + w * 16;
    const h16x8 hzero = {0, 0, 0, 0, 0, 0, 0, 0};

#pragma unroll
    for (int e = 0; e < (NB * AB) / 256; ++e) ((float*)att_s)[tid + e * 256] = 0.0f;

#pragma unroll 1
    for (int lh = 0; lh < hpb; ++lh) {
        int bufh = hb + lh;                 // index into HXh / dhx
        int h = h0 + bufh;                  // global head
        __syncthreads();                    // protect hxs/score_s from prev readers
        {   // stage hxs: 16KB contiguous copy
            const h16x8* src = (const h16x8*)(HXh + ((size_t)bufh * NROWS + n0) * FD);
            h16x8 v0 = src[tid], v1 = src[tid + 256], v2 = src[tid + 512], v3 = src[tid + 768];
            h16x8* d = (h16x8*)&hxs[0][0];
            d[tid] = v0; d[tid + 256] = v1; d[tid + 512] = v2; d[tid + 768] = v3;
        }
        if (tid < NB) dhx_s[tid] = dhx[(size_t)bufh * NROWS + n0 + tid];
        if (tid >= 64 && tid < 64 + AB) dga_s[tid - 64] = dga[h * NA + a0 + (tid - 64)];
        // per-lane fragments (live across the n-loop)
        h16x8 gfrag[8], bfrag[8];
#pragma unroll
        for (int fc = 0; fc < 8; ++fc) {
            gfrag[fc] = *(const h16x8*)(Gh + ((size_t)(h * NA + a_base + arow)) * FD + fc * 32 + grp * 8);
            bfrag[fc] = (arow == 0)
                ? *(const h16x8*)(W2h + h * FD + fc * 32 + grp * 8)
                : hzero;
        }
        __syncthreads();
#pragma unroll 1
        for (int n = 0; n < NB; n += 2) {
            f32x4 acc0 = {0, 0, 0, 0}, acc1 = {0, 0, 0, 0};
#pragma unroll
            for (int fc = 0; fc < 8; ++fc) {
                h16x8 hx0 = *(const h16x8*)&hxs[n][fc * 32 + grp * 8];
                h16x8 hx1 = *(const h16x8*)&hxs[n + 1][fc * 32 + grp * 8];
                acc0 = __builtin_amdgcn_mfma_f32_16x16x32_f16(absadd(hx0, gfrag[fc]), bfrag[fc], acc0, 0, 0, 0);
                acc1 = __builtin_amdgcn_mfma_f32_16x16x32_f16(absadd(hx1, gfrag[fc]), bfrag[fc], acc1, 0, 0, 0);
            }
            if (arow == 0) {   // D col0: row a = grp*4 + r
                h16x4 s0 = {(_Float16)acc0.x, (_Float16)acc0.y, (_Float16)acc0.z, (_Float16)acc0.w};
                h16x4 s1 = {(_Float16)acc1.x, (_Float16)acc1.y, (_Float16)acc1.z, (_Float16)acc1.w};
                *(h16x4*)&score_s[n][w * 16 + grp * 4]     = s0;
                *(h16x4*)&score_s[n + 1][w * 16 + grp * 4] = s1;
            }
        }
        __syncthreads();
#pragma unroll
        for (int e = 0; e < (NB * AB) / 256; ++e) {
            int idx = tid + e * 256, n = idx >> 6, a = idx & 63;
            float sc = (float)score_s[n][a] + dhx_s[n] + dga_s[a];
            att_s[n][a] += 1.0f / (1.0f + __expf(-sc));
        }
    }
    __syncthreads();
#pragma unroll
    for (int e = 0; e < (NB * AB) / 256; ++e) {
        int idx = tid + e * 256, n = idx >> 6, a = idx & 63;
        atomicAdd(&out[(size_t)(n0 + n) * NA + a0 + a], att_s[n][a] * (1.0f / 16.0f));
    }
}

extern "C" void kernel_launch(void* const* d_in, const int* in_sizes, int n_in,
                              void* d_out, int out_size, void* d_ws, size_t ws_size,
                              hipStream_t stream) {
    const float* ctx     = (const float*)d_in[0];
    const float* anchors = (const float*)d_in[1];
    const float* W1      = (const float*)d_in[2];
    const float* b1      = (const float*)d_in[3];
    const float* W2      = (const float*)d_in[4];
    const float* b2      = (const float*)d_in[5];
    float* out = (float*)d_out;
    char* ws = (char*)d_ws;

    const size_t SZ_G   = (size_t)NH * NA * FD * 2;
    const size_t SZ_XB  = (size_t)NROWS * FD * 2;
    const size_t SZ_WB  = (size_t)NH * FD * FD * 2;
    const size_t SZ_W2  = (size_t)NH * FD * 2;
    const size_t SZ_DGA = (size_t)NH * NA * 4;
    const size_t SZ_DHX = (size_t)NH * NROWS * 4;
    const size_t SZ_HX1 = (size_t)NROWS * FD * 2;
    const size_t fixed = SZ_G + SZ_XB + SZ_WB + SZ_W2 + SZ_DGA + SZ_DHX;

    int HG;
    if      (ws_size >= fixed + 16 * SZ_HX1) HG = 16;
    else if (ws_size >= fixed + 4 * SZ_HX1)  HG = 4;
    else if (ws_size >= fixed + 2 * SZ_HX1)  HG = 2;
    else                                      HG = 1;

    _Float16* Gh       = (_Float16*)(ws);
    unsigned short* Xb = (unsigned short*)(ws + SZ_G);
    unsigned short* Wb = (unsigned short*)(ws + SZ_G + SZ_XB);
    _Float16* W2h      = (_Float16*)(ws + SZ_G + SZ_XB + SZ_WB);
    float* dga         = (float*)(ws + SZ_G + SZ_XB + SZ_WB + SZ_W2);
    float* dhx         = (float*)(ws + SZ_G + SZ_XB + SZ_WB + SZ_W2 + SZ_DGA);
    _Float16* HXh      = (_Float16*)(ws + fixed);

    hipMemsetAsync(out, 0, (size_t)NROWS * NA * sizeof(float), stream);
    cvt_x_kernel<<<1024, 256, 0, stream>>>(ctx, Xb);
    cvt_w_kernel<<<512, 256, 0, stream>>>(W1, Wb);
    cvt_w2_kernel<<<16, 256, 0, stream>>>(W2, W2h);
    g_kernel<<<dim3(16, 4, 4), 256, 0, stream>>>(anchors, W1, b1, Gh);
    dga_kernel<<<16, 256, 0, stream>>>(Gh, W2h, b2, dga);

    for (int h0 = 0; h0 < NH; h0 += HG) {
        hx_kernel<<<dim3(64, HG * 2), 256, 0, stream>>>(Xb, Wb, HXh, h0);
        dhx_kernel<<<dim3(128, HG), 256, 0, stream>>>(HXh, W2h, dhx, h0);
        int hpb = (HG >= 4) ? 4 : HG;       // heads per main-block
        main6_kernel<<<dim3(NROWS / NB, NA / AB, HG / hpb), 256, 0, stream>>>(
            HXh, Gh, W2h, dhx, dga, out, h0, hpb);
    }
    hipMemcpyAsync(out + (size_t)NROWS * NA, anchors, (size_t)NA * FD * sizeof(float),
                   hipMemcpyDeviceToDevice, stream);
}